// Round 1
// baseline (274.632 us; speedup 1.0000x reference)
//
#include <hip/hip_runtime.h>

typedef __bf16 bf16x8 __attribute__((ext_vector_type(8)));
typedef float f32x4 __attribute__((ext_vector_type(4)));
typedef unsigned int u32x4 __attribute__((ext_vector_type(4)));
typedef unsigned short u16;

#define MFMA16(A, B, C) __builtin_amdgcn_mfma_f32_16x16x32_bf16((A), (B), (C), 0, 0, 0)

// exp(x) = exp2(x*log2e); scores get HD^-0.5 folded in.
#define KEXP   (0.17677669529663687f * 1.4426950408889634f)
#define LOG2E  1.4426950408889634f
#define LAMI   0.35550906759096926f           // LAMBDA_INIT = 0.8 - 0.6*exp(-0.3)
#define ONEML  0.6444909324090307f            // 1 - LAMBDA_INIT

static __device__ __forceinline__ u16 bf16b(float v) {
  __bf16 b = (__bf16)v;
  return __builtin_bit_cast(u16, b);
}

static __device__ __forceinline__ bf16x8 f32frag(const float* p) {
  float4 a = *(const float4*)p;
  float4 b = *(const float4*)(p + 4);
  bf16x8 r;
  r[0] = (__bf16)a.x; r[1] = (__bf16)a.y; r[2] = (__bf16)a.z; r[3] = (__bf16)a.w;
  r[4] = (__bf16)b.x; r[5] = (__bf16)b.y; r[6] = (__bf16)b.z; r[7] = (__bf16)b.w;
  return r;
}

// ---------------- sigma -> s_val [B,H,L] ----------------
__global__ __launch_bounds__(256) void sigma_kernel(const float* __restrict__ q,
                                                    const float* __restrict__ Ws,
                                                    const float* __restrict__ bsig,
                                                    float* __restrict__ s_val) {
  int t = blockIdx.x * 256 + threadIdx.x;  // 32768 = 2048 tok * 16 h
  int tok = t >> 4, h = t & 15;
  const float* qr = q + (size_t)tok * 1024;
  const float* wr = Ws + (size_t)h * 1024;
  float acc = 0.f;
  for (int k = 0; k < 1024; k += 4) {
    float4 a = *(const float4*)(qr + k);
    float4 b = *(const float4*)(wr + k);
    acc += a.x * b.x + a.y * b.y + a.z * b.z + a.w * b.w;
  }
  float sg = acc + bsig[h];
  float sig = 1.f / (1.f + __expf(-5.f * sg));
  float sv = exp2f(1.5849625007211562f * (sig + 1e-5f)) - 1.f;  // 3^x - 1
  s_val[((size_t)(tok >> 10) * 16 + h) * 1024 + (tok & 1023)] = sv;
}

// ---------------- fused projection GEMMs (B^T form, f32 operands -> bf16 frags) ----
// bid<256: Q = queries@Wq^T -> Qh[b,2H,L,32]; bid<384: K = keys@Wk^T -> Kh[b,16,L,32]
// else   : Vt = Wv@values^T -> Vt[b,8,64,1024]  (pre-transposed V)
__global__ __launch_bounds__(256) void proj_kernel(
    const float* __restrict__ queries, const float* __restrict__ keys,
    const float* __restrict__ values, const float* __restrict__ Wq,
    const float* __restrict__ Wk, const float* __restrict__ Wv,
    u16* __restrict__ Qh, u16* __restrict__ Kh, u16* __restrict__ Vt) {
  int bid = blockIdx.x;
  const float *A, *Bm;
  int mb, nb, epi;
  if (bid < 256)      { A = queries; Bm = Wq;     mb = bid >> 4;          nb = bid & 15;          epi = 0; }
  else if (bid < 384) { A = keys;    Bm = Wk;     mb = (bid - 256) >> 3;  nb = (bid - 256) & 7;   epi = 1; }
  else                { A = Wv;      Bm = values; mb = (bid - 384) >> 5;  nb = (bid - 384) & 31;  epi = 2; }
  int lane = threadIdx.x & 63, w = threadIdx.x >> 6;
  int g = lane >> 4, cc = lane & 15;
  int mw = mb * 128 + (w >> 1) * 64;
  int nw = nb * 64 + (w & 1) * 32;
  f32x4 acc[4][2] = {};
  const float* Ab = A + (size_t)(mw + cc) * 1024 + g * 8;
  const float* Bb = Bm + (size_t)(nw + cc) * 1024 + g * 8;
  for (int kk = 0; kk < 1024; kk += 32) {
    bf16x8 af[4], bfr[2];
#pragma unroll
    for (int fm = 0; fm < 4; ++fm) af[fm] = f32frag(Ab + (size_t)fm * 16384 + kk);
#pragma unroll
    for (int fn = 0; fn < 2; ++fn) bfr[fn] = f32frag(Bb + (size_t)fn * 16384 + kk);
#pragma unroll
    for (int fm = 0; fm < 4; ++fm)
#pragma unroll
      for (int fn = 0; fn < 2; ++fn) acc[fm][fn] = MFMA16(af[fm], bfr[fn], acc[fm][fn]);
  }
#pragma unroll
  for (int fm = 0; fm < 4; ++fm)
#pragma unroll
    for (int fn = 0; fn < 2; ++fn)
#pragma unroll
      for (int r = 0; r < 4; ++r) {
        int row = mw + fm * 16 + 4 * g + r;
        int col = nw + fn * 16 + cc;
        u16 u = bf16b(acc[fm][fn][r]);
        if (epi == 0) {
          int b = row >> 10, l = row & 1023;
          Qh[((size_t)(b * 32 + (col >> 5)) * 1024 + l) * 32 + (col & 31)] = u;
        } else if (epi == 1) {
          int b = row >> 10, l = row & 1023;
          Kh[((size_t)(b * 16 + (col >> 5)) * 1024 + l) * 32 + (col & 31)] = u;
        } else {  // row = dv(0..511), col = token
          Vt[((size_t)(col >> 10) * 512 + row) * 1024 + (col & 1023)] = u;
        }
      }
}

// ---------------- fused differential attention + series + prior/s fill ----------------
__global__ __launch_bounds__(256) void attn_kernel(
    const u16* __restrict__ Qh, const u16* __restrict__ Kh, const u16* __restrict__ Vt,
    const float* __restrict__ s_val, const float* __restrict__ lq1,
    const float* __restrict__ lk1, const float* __restrict__ lq2,
    const float* __restrict__ lk2, const float* __restrict__ gvec,
    float* __restrict__ series, float* __restrict__ prior, float* __restrict__ sOut,
    u16* __restrict__ Vn) {
  __shared__ u16 Klds[32768];      // full K head, 64KB, (row&3) xor-swizzled
  __shared__ u16 Plds[4][1024];    // per-wave P tile [16 i][64-elem row, 32 used], swizzled

  int bid = blockIdx.x;
  // balanced (rt, bh) decode: CU gets bid and bid+256 -> rt pairs summing to 15
  int hi = bid >> 8, mid = (bid >> 4) & 15, lo = bid & 15;
  int rt = hi ? (15 - mid) : mid;
  int bh = hi * 16 + lo;
  int b = bh >> 4, h = bh & 15;

  int tid = threadIdx.x;
  int w = tid >> 6, lane = tid & 63, g = lane >> 4, cc = lane & 15;
  int i0 = rt * 64 + w * 16;  // this wave's 16 rows

  // lambda (uniform)
  float d1 = 0.f, d2 = 0.f;
#pragma unroll
  for (int t = 0; t < 32; ++t) { d1 += lq1[t] * lk1[t]; d2 += lq2[t] * lk2[t]; }
  const float lam = __expf(d1) - __expf(d2) + LAMI;

  // stage K head rows [0, (rt+1)*64) into LDS
  {
    const u16* Ks = Kh + (size_t)(b * 16 + h) * 32768;
    int nelem = (rt + 1) * 2048;
    for (int off = tid * 8; off < nelem; off += 2048) {
      int row = off >> 5;
      int ch8 = (off >> 3) & 3;
      int dst = row * 32 + ((ch8 * 8) ^ ((row & 3) << 3));
      *(u32x4*)&Klds[dst] = *(const u32x4*)&Ks[off];
    }
  }
  __syncthreads();

  const bf16x8 q0 = *(const bf16x8*)(Qh + ((size_t)(b * 32 + 2 * h) * 1024 + i0 + cc) * 32 + g * 8);
  const bf16x8 q1 = *(const bf16x8*)(Qh + ((size_t)(b * 32 + 2 * h + 1) * 1024 + i0 + cc) * 32 + g * 8);

  const int nt = (i0 >> 4) + 1;
  const f32x4 zf = {0.f, 0.f, 0.f, 0.f};
  const int iC = i0 + cc;  // column-form row index (S^T layout: col = query row)

#define KFRAG(jt) (*(const bf16x8*)&Klds[((jt)*16 + cc) * 32 + ((8 * g) ^ ((cc & 3) << 3))])

  // ---- sweep 1: softmax denominators z0, z1 (fixed max = 0) ----
  float z0 = 0.f, z1 = 0.f;
  for (int jt = 0; jt < nt; ++jt) {
    bf16x8 kf = KFRAG(jt);
    f32x4 s0 = MFMA16(kf, q0, zf);  // S^T: row = key j, col = query i
    f32x4 s1 = MFMA16(kf, q1, zf);
#pragma unroll
    for (int r = 0; r < 4; ++r) {
      int j = jt * 16 + 4 * g + r;
      float e0 = exp2f(s0[r] * KEXP);
      float e1 = exp2f(s1[r] * KEXP);
      if (j <= iC) { z0 += e0; z1 += e1; }
    }
  }
  z0 += __shfl_xor(z0, 16); z0 += __shfl_xor(z0, 32);
  z1 += __shfl_xor(z1, 16); z1 += __shfl_xor(z1, 32);
  const float iz0 = 1.f / z0;
  const float iz1n = lam / z1;

  // ---- sweep 2: aw -> P (LDS, bf16) -> PV MFMA; ZA accumulation ----
  f32x4 acc[4] = {zf, zf, zf, zf};
  float za = 0.f;
  const u16* Vb = Vt + (size_t)(b * 8 + (h >> 1)) * 65536;
  for (int jt0 = 0; jt0 < nt; jt0 += 2) {
#pragma unroll
    for (int t = 0; t < 2; ++t) {
      int jt = jt0 + t;
      if (jt < nt) {
        bf16x8 kf = KFRAG(jt);
        f32x4 s0 = MFMA16(kf, q0, zf);
        f32x4 s1 = MFMA16(kf, q1, zf);
#pragma unroll
        for (int r = 0; r < 4; ++r) {
          int j = jt * 16 + 4 * g + r;
          float awv = exp2f(s0[r] * KEXP) * iz0 - exp2f(s1[r] * KEXP) * iz1n;
          bool ok = (j <= iC);
          za += ok ? exp2f(awv * LOG2E) : 0.f;
          int jl = t * 16 + 4 * g + r;
          Plds[w][cc * 64 + (jl ^ ((cc & 7) << 3))] = bf16b(ok ? awv : 0.f);
        }
      } else {
#pragma unroll
        for (int r = 0; r < 4; ++r) {
          int jl = 16 + 4 * g + r;
          Plds[w][cc * 64 + (jl ^ ((cc & 7) << 3))] = 0;
        }
      }
    }
    // intra-wave cross-lane LDS RAW: force drain (compiler won't, addresses differ per lane)
    asm volatile("s_waitcnt lgkmcnt(0)" ::: "memory");
    bf16x8 pa = *(const bf16x8*)&Plds[w][cc * 64 + ((8 * g) ^ ((cc & 7) << 3))];
    int jb = jt0 * 16 + g * 8;
#pragma unroll
    for (int ds = 0; ds < 4; ++ds) {
      bf16x8 vf = *(const bf16x8*)(Vb + (size_t)(ds * 16 + cc) * 1024 + jb);
      acc[ds] = MFMA16(pa, vf, acc[ds]);  // D[i][d]: row=i, col=d
    }
  }
  za += __shfl_xor(za, 16); za += __shfl_xor(za, 32);

  // ---- RMSNorm over d=64 + Vn store (bf16) ----
  float ss[4];
#pragma unroll
  for (int r = 0; r < 4; ++r) {
    float s = 0.f;
#pragma unroll
    for (int ds = 0; ds < 4; ++ds) s += acc[ds][r] * acc[ds][r];
    s += __shfl_xor(s, 1); s += __shfl_xor(s, 2);
    s += __shfl_xor(s, 4); s += __shfl_xor(s, 8);
    ss[r] = s;
  }
  float gw[4];
#pragma unroll
  for (int ds = 0; ds < 4; ++ds) gw[ds] = gvec[ds * 16 + cc];
#pragma unroll
  for (int r = 0; r < 4; ++r) {
    float rs = rsqrtf(ss[r] * (1.f / 64.f) + 1e-5f) * ONEML;
    int irow = i0 + 4 * g + r;
#pragma unroll
    for (int ds = 0; ds < 4; ++ds) {
      float v = acc[ds][r] * rs * gw[ds];
      Vn[(size_t)(b * 1024 + irow) * 1024 + h * 64 + ds * 16 + cc] = bf16b(v);
    }
  }

  // ---- sweep 3: series (unswapped QK^T so rows = i -> coalesced stores) ----
  float iz0r[4], iz1r[4], izar[4];
#pragma unroll
  for (int r = 0; r < 4; ++r) {
    int src = 4 * g + r;
    iz0r[r] = __shfl(iz0, src);
    iz1r[r] = __shfl(iz1n, src);
    float zar = __shfl(za, src);
    izar[r] = 1.f / (zar + (float)(1023 - (i0 + 4 * g + r)));
  }
  float* srow = series + ((size_t)(b * 16 + h) << 20);
  for (int jt = 0; jt < nt; ++jt) {
    bf16x8 kf = KFRAG(jt);
    f32x4 s0 = MFMA16(q0, kf, zf);  // D[i][j]
    f32x4 s1 = MFMA16(q1, kf, zf);
#pragma unroll
    for (int r = 0; r < 4; ++r) {
      int irow = i0 + 4 * g + r;
      int j = jt * 16 + cc;
      float awv = exp2f(s0[r] * KEXP) * iz0r[r] - exp2f(s1[r] * KEXP) * iz1r[r];
      float v = (j <= irow) ? exp2f(awv * LOG2E) * izar[r] : izar[r];
      srow[(size_t)irow * 1024 + j] = v;
    }
  }
  // tail: masked region beyond this wave's tiles = constant 1/ZA per row
  int jend = nt * 16;
  for (int rr = 0; rr < 16; ++rr) {
    int irow = i0 + rr;
    float zar = __shfl(za, rr);
    float fv = 1.f / (zar + (float)(1023 - irow));
    float4 f4 = {fv, fv, fv, fv};
    float* p = srow + (size_t)irow * 1024;
    for (int j = jend + lane * 4; j < 1024; j += 256) *(float4*)(p + j) = f4;
  }

  // ---- prior + s outputs for this wave's 16 rows ----
  const float* svp = s_val + (size_t)(b * 16 + h) * 1024;
  float* prow = prior + ((size_t)(b * 16 + h) << 20);
  float* sorow = sOut + ((size_t)(b * 16 + h) << 20);
  for (int rr = 0; rr < 16; ++rr) {
    int irow = i0 + rr;
    float sv = svp[irow];
    float c1 = 0.3989422804014327f / sv;               // 1/(sqrt(2pi)*s)
    float c2 = -0.7213475204444817f / (sv * sv);       // -log2e/(2 s^2)
    float4 s4 = {sv, sv, sv, sv};
    size_t base = (size_t)irow * 1024;
    for (int j0 = lane * 4; j0 < 1024; j0 += 256) {
      float4 pv;
      float dd;
      dd = (float)(irow - j0);       pv.x = c1 * exp2f(c2 * dd * dd);
      dd = (float)(irow - (j0 + 1)); pv.y = c1 * exp2f(c2 * dd * dd);
      dd = (float)(irow - (j0 + 2)); pv.z = c1 * exp2f(c2 * dd * dd);
      dd = (float)(irow - (j0 + 3)); pv.w = c1 * exp2f(c2 * dd * dd);
      *(float4*)(prow + base + j0) = pv;
      *(float4*)(sorow + base + j0) = s4;
    }
  }
#undef KFRAG
}

// ---------------- out = Vn @ Wo^T ----------------
__global__ __launch_bounds__(256) void wo_kernel(const u16* __restrict__ Vn,
                                                 const float* __restrict__ Wo,
                                                 float* __restrict__ out) {
  int bid = blockIdx.x;
  int mb = bid >> 4, nb = bid & 15;
  int lane = threadIdx.x & 63, w = threadIdx.x >> 6;
  int g = lane >> 4, cc = lane & 15;
  int mw = mb * 128 + (w >> 1) * 64;
  int nw = nb * 64 + (w & 1) * 32;
  f32x4 acc[4][2] = {};
  const u16* Ab = Vn + (size_t)(mw + cc) * 1024 + g * 8;
  const float* Bb = Wo + (size_t)(nw + cc) * 1024 + g * 8;
  for (int kk = 0; kk < 1024; kk += 32) {
    bf16x8 af[4], bfr[2];
#pragma unroll
    for (int fm = 0; fm < 4; ++fm) af[fm] = *(const bf16x8*)(Ab + (size_t)fm * 16384 + kk);
#pragma unroll
    for (int fn = 0; fn < 2; ++fn) bfr[fn] = f32frag(Bb + (size_t)fn * 16384 + kk);
#pragma unroll
    for (int fm = 0; fm < 4; ++fm)
#pragma unroll
      for (int fn = 0; fn < 2; ++fn) acc[fm][fn] = MFMA16(af[fm], bfr[fn], acc[fm][fn]);
  }
#pragma unroll
  for (int fm = 0; fm < 4; ++fm)
#pragma unroll
    for (int fn = 0; fn < 2; ++fn)
#pragma unroll
      for (int r = 0; r < 4; ++r) {
        int row = mw + fm * 16 + 4 * g + r;
        int col = nw + fn * 16 + cc;
        out[(size_t)row * 1024 + col] = acc[fm][fn][r];
      }
}

extern "C" void kernel_launch(void* const* d_in, const int* in_sizes, int n_in,
                              void* d_out, int out_size, void* d_ws, size_t ws_size,
                              hipStream_t stream) {
  (void)in_sizes; (void)n_in; (void)out_size; (void)ws_size;
  const float* queries = (const float*)d_in[0];
  const float* keys    = (const float*)d_in[1];
  const float* values  = (const float*)d_in[2];
  // d_in[3] = attn_mask: deterministic causal triu, not needed
  const float* Wq   = (const float*)d_in[4];
  const float* Wk   = (const float*)d_in[5];
  const float* Wv   = (const float*)d_in[6];
  const float* Wo   = (const float*)d_in[7];
  const float* Ws   = (const float*)d_in[8];
  const float* bsig = (const float*)d_in[9];
  const float* lq1  = (const float*)d_in[10];
  const float* lk1  = (const float*)d_in[11];
  const float* lq2  = (const float*)d_in[12];
  const float* lk2  = (const float*)d_in[13];
  const float* gvec = (const float*)d_in[14];

  float* out0       = (float*)d_out;
  float* out_series = out0 + 2097152;
  float* out_prior  = out_series + 33554432;
  float* out_s      = out_prior + 33554432;

  char* ws = (char*)d_ws;
  u16*  Qh    = (u16*)(ws);                       // [2,32,1024,32] bf16, 4MB
  u16*  Kh    = (u16*)(ws + (4ull << 20));        // [2,16,1024,32] bf16, 2MB
  u16*  Vt    = (u16*)(ws + (6ull << 20));        // [2,8,64,1024]  bf16, 2MB
  u16*  Vn    = (u16*)(ws + (8ull << 20));        // [2048,1024]    bf16, 4MB
  float* s_val = (float*)(ws + (12ull << 20));    // [2,16,1024]    f32, 128KB

  sigma_kernel<<<128, 256, 0, stream>>>(queries, Ws, bsig, s_val);
  proj_kernel<<<512, 256, 0, stream>>>(queries, keys, values, Wq, Wk, Wv, Qh, Kh, Vt);
  attn_kernel<<<512, 256, 0, stream>>>(Qh, Kh, Vt, s_val, lq1, lk1, lq2, lk2, gvec,
                                       out_series, out_prior, out_s, Vn);
  wo_kernel<<<256, 256, 0, stream>>>(Vn, Wo, out0);
}